// Round 5
// baseline (253.830 us; speedup 1.0000x reference)
//
#include <hip/hip_runtime.h>
#include <hip/hip_cooperative_groups.h>
#include <math.h>

#define BB 32
#define HH 56
#define WW 56
#define CC 256
#define KS 7
#define NPIX (BB * HH * WW)   // 100352

#define GRID 2048             // 8 blocks/CU * 256 CUs; co-residency forced below
#define NWAVES (GRID * 4)     // 8192 persistent waves

typedef float vfloat4 __attribute__((ext_vector_type(4)));

namespace cg = cooperative_groups;

// ---------------------------------------------------------------------------
// Single cooperative kernel, two phases separated by grid.sync():
//  phase 1: channel avg+max pool (one wave per pixel, grid-stride ~12 iters)
//  phase 2: 7x7 conv + sigmoid + multiply (one wave per pixel, grid-stride)
// __launch_bounds__(256, 8) forces VGPR<=64 so 8 blocks/CU are guaranteed
// co-resident -> grid sync cannot deadlock at GRID=2048.
// ---------------------------------------------------------------------------
__global__ __launch_bounds__(256, 8) void spatial_attn_all(
    const float* __restrict__ x,
    float2* __restrict__ pooled,
    const float2* __restrict__ cwv,
    float* __restrict__ out)
{
    const int wave = threadIdx.x >> 6;
    const int lane = threadIdx.x & 63;
    const int wid = blockIdx.x * 4 + wave;

    // ---- phase 1: pooling ----
    for (int pix = wid; pix < NPIX; pix += NWAVES) {
        const vfloat4 v = reinterpret_cast<const vfloat4*>(x)[(size_t)pix * (CC / 4) + lane];
        float s = v.x + v.y + v.z + v.w;
        float m = fmaxf(fmaxf(v.x, v.y), fmaxf(v.z, v.w));
#pragma unroll
        for (int off = 32; off > 0; off >>= 1) {
            s += __shfl_down(s, off, 64);
            m = fmaxf(m, __shfl_down(m, off, 64));
        }
        if (lane == 0) pooled[pix] = make_float2(s * (1.0f / CC), m);
    }

    cg::this_grid().sync();

    // ---- phase 2: conv + sigmoid + multiply ----
    // loop-invariant per-lane tap setup
    float2 w = make_float2(0.0f, 0.0f);
    int ky = 0, kx = 0;
    if (lane < KS * KS) {
        ky = lane / KS;
        kx = lane - ky * KS;
        w = cwv[lane];
    }

    for (int pix = wid; pix < NPIX; pix += NWAVES) {
        const size_t i = (size_t)pix * (CC / 4) + lane;
        const vfloat4 v = reinterpret_cast<const vfloat4*>(x)[i];  // issue early

        const int wcol = pix % WW;
        const int t = pix / WW;
        const int hrow = t % HH;
        const int b = t / HH;

        float partial = 0.0f;
        if (lane < KS * KS) {
            const int yy = hrow + ky - 3;
            const int xx = wcol + kx - 3;
            if (yy >= 0 && yy < HH && xx >= 0 && xx < WW) {
                const float2 p = pooled[((size_t)b * HH + yy) * WW + xx];
                partial = fmaf(p.x, w.x, p.y * w.y);
            }
        }
#pragma unroll
        for (int off = 1; off < 64; off <<= 1) {
            partial += __shfl_xor(partial, off, 64);
        }
        const float att = 1.0f / (1.0f + expf(-partial));

        const vfloat4 o = v * att;
        reinterpret_cast<vfloat4*>(out)[i] = o;
    }
}

extern "C" void kernel_launch(void* const* d_in, const int* in_sizes, int n_in,
                              void* d_out, int out_size, void* d_ws, size_t ws_size,
                              hipStream_t stream) {
    const float* x = (const float*)d_in[0];
    const float2* cw = (const float2*)d_in[1];
    float* out = (float*)d_out;
    float2* pooled = (float2*)d_ws;

    void* args[] = {(void*)&x, (void*)&pooled, (void*)&cw, (void*)&out};
    hipLaunchCooperativeKernel((void*)spatial_attn_all, dim3(GRID), dim3(256),
                               args, 0, stream);
}

// Round 6
// 51.259 us; speedup vs baseline: 4.9519x; 4.9519x over previous
//
#include <hip/hip_runtime.h>
#include <math.h>

#define BB 32
#define HH 56
#define WW 56
#define CC 256
#define KS 7
#define NPIX (BB * HH * WW)   // 100352
#define NWPAIR (NPIX / 2)     // 50176 wave-jobs (2 pixels each)

typedef float vfloat4 __attribute__((ext_vector_type(4)));

// ---------------------------------------------------------------------------
// DPP wave64 reductions (rocPRIM pattern): no DS ops, pure VALU.
// Result accumulates into lane 63, then readlane-broadcast -> SGPR uniform.
// ---------------------------------------------------------------------------
template <int CTRL, int RM, int BM>
__device__ __forceinline__ float dpp_add(float v) {
    const int iv = __float_as_int(v);
    const int sh = __builtin_amdgcn_update_dpp(iv, iv, CTRL, RM, BM, false);
    return v + __int_as_float(sh);
}
template <int CTRL, int RM, int BM>
__device__ __forceinline__ float dpp_max(float v) {
    const int iv = __float_as_int(v);
    const int sh = __builtin_amdgcn_update_dpp(iv, iv, CTRL, RM, BM, false);
    return fmaxf(v, __int_as_float(sh));
}

__device__ __forceinline__ float wave_sum(float s) {
    s = dpp_add<0x111, 0xf, 0xf>(s);  // row_shr:1
    s = dpp_add<0x112, 0xf, 0xf>(s);  // row_shr:2
    s = dpp_add<0x114, 0xf, 0xe>(s);  // row_shr:4, bank_mask 0xe
    s = dpp_add<0x118, 0xf, 0xc>(s);  // row_shr:8, bank_mask 0xc
    s = dpp_add<0x142, 0xa, 0xf>(s);  // row_bcast:15, rows 1,3
    s = dpp_add<0x143, 0xc, 0xf>(s);  // row_bcast:31, rows 2,3
    return __int_as_float(__builtin_amdgcn_readlane(__float_as_int(s), 63));
}
__device__ __forceinline__ float wave_max(float m) {
    m = dpp_max<0x111, 0xf, 0xf>(m);
    m = dpp_max<0x112, 0xf, 0xf>(m);
    m = dpp_max<0x114, 0xf, 0xe>(m);
    m = dpp_max<0x118, 0xf, 0xc>(m);
    m = dpp_max<0x142, 0xa, 0xf>(m);
    m = dpp_max<0x143, 0xc, 0xf>(m);
    return __int_as_float(__builtin_amdgcn_readlane(__float_as_int(m), 63));
}

// ---------------------------------------------------------------------------
// Kernel 1: avg+max pool, TWO pixels per wave. Two independent coalesced 1KB
// loads, local reduce, DPP wave reduce (no DS), one 16B store by lane 0
// (pooled[2w] and pooled[2w+1] are adjacent float2s -> single float4).
// ---------------------------------------------------------------------------
__global__ __launch_bounds__(256) void pool_kernel(const float* __restrict__ x,
                                                   float4* __restrict__ pooled4) {
    const int wave = threadIdx.x >> 6;
    const int lane = threadIdx.x & 63;
    const int wid = blockIdx.x * 4 + wave;   // wave-pair id, < NWPAIR

    const size_t base = (size_t)wid * 128 + lane;
    const vfloat4 v0 = reinterpret_cast<const vfloat4*>(x)[base];
    const vfloat4 v1 = reinterpret_cast<const vfloat4*>(x)[base + 64];

    float s0 = (v0.x + v0.y) + (v0.z + v0.w);
    float m0 = fmaxf(fmaxf(v0.x, v0.y), fmaxf(v0.z, v0.w));
    float s1 = (v1.x + v1.y) + (v1.z + v1.w);
    float m1 = fmaxf(fmaxf(v1.x, v1.y), fmaxf(v1.z, v1.w));

    s0 = wave_sum(s0);
    s1 = wave_sum(s1);
    m0 = wave_max(m0);
    m1 = wave_max(m1);

    if (lane == 0) {
        pooled4[wid] = make_float4(s0 * (1.0f / CC), m0, s1 * (1.0f / CC), m1);
    }
}

// ---------------------------------------------------------------------------
// Kernel 2: fused conv+sigmoid+multiply, TWO pixels per wave (adjacent cols,
// same row: pix0 even so wcol0<=54, pix1 never wraps). Lanes 0..48 each take
// one 7x7 tap for both pixels (adjacent pooled loads, L1-hot). DPP sum
// reduce, sigmoid, scale both 1KB x blocks, store 2KB.
// ---------------------------------------------------------------------------
__global__ __launch_bounds__(256) void fused_kernel(const float* __restrict__ x,
                                                    const float2* __restrict__ pooled,
                                                    const float2* __restrict__ cwv,
                                                    float* __restrict__ out) {
    const int wave = threadIdx.x >> 6;
    const int lane = threadIdx.x & 63;
    const int wid = blockIdx.x * 4 + wave;

    // issue both x loads first (independent of everything below)
    const size_t base = (size_t)wid * 128 + lane;
    const vfloat4 v0 = reinterpret_cast<const vfloat4*>(x)[base];
    const vfloat4 v1 = reinterpret_cast<const vfloat4*>(x)[base + 64];

    const int pix0 = wid * 2;
    const int wcol0 = pix0 % WW;          // even, <= 54
    const int t = pix0 / WW;
    const int hrow = t % HH;
    const int b = t / HH;

    float pa = 0.0f, pb = 0.0f;
    if (lane < KS * KS) {
        const int ky = lane / KS;
        const int kx = lane - ky * KS;
        const int yy = hrow + ky - 3;
        if (yy >= 0 && yy < HH) {
            const float2* __restrict__ row = pooled + ((size_t)b * HH + yy) * WW;
            const float2 w = cwv[lane];
            const int xx0 = wcol0 + kx - 3;
            const int xx1 = xx0 + 1;
            if (xx0 >= 0 && xx0 < WW) {
                const float2 p = row[xx0];
                pa = fmaf(p.x, w.x, p.y * w.y);
            }
            if (xx1 >= 0 && xx1 < WW) {
                const float2 p = row[xx1];
                pb = fmaf(p.x, w.x, p.y * w.y);
            }
        }
    }
    pa = wave_sum(pa);
    pb = wave_sum(pb);
    const float att0 = 1.0f / (1.0f + expf(-pa));
    const float att1 = 1.0f / (1.0f + expf(-pb));

    reinterpret_cast<vfloat4*>(out)[base]      = v0 * att0;
    reinterpret_cast<vfloat4*>(out)[base + 64] = v1 * att1;
}

extern "C" void kernel_launch(void* const* d_in, const int* in_sizes, int n_in,
                              void* d_out, int out_size, void* d_ws, size_t ws_size,
                              hipStream_t stream) {
    const float* x = (const float*)d_in[0];
    const float2* cw = (const float2*)d_in[1];
    float* out = (float*)d_out;
    float2* pooled = (float2*)d_ws;

    const int grid = NWPAIR / 4;  // 12544 blocks, 4 wave-jobs each
    pool_kernel<<<grid, 256, 0, stream>>>(x, (float4*)pooled);
    fused_kernel<<<grid, 256, 0, stream>>>(x, pooled, cw, out);
}